// Round 1
// baseline (1403.371 us; speedup 1.0000x reference)
//
#include <hip/hip_runtime.h>
#include <hip/hip_bf16.h>

// CGConv fused for MI355X (gfx950) — round 6.
//   gemm: B-matrix (96 KB bpack) staged ONCE per block into LDS; 768-thread
//         (12-wave) blocks grid-stride over 384-edge batches with no barriers
//         in steady state. Kills the 2.4 GB of per-wave L2 re-reads of bpack
//         that left MfmaUtil at 11%. B reads are contiguous ds_read_b128
//         (conflict-free). Everything else unchanged from round 5.
//   CSR:  scatter produces inverse-perm rank[e]; gemm writes msg rows directly
//         at CSR position -> aggregate is a contiguous vectorized stream.

#define NODE_DIM 96
#define EDGE_DIM 64
#define IN_DIM   256
#define NT_TILES 12       // 192 output cols = 96 gates + 96 msgs
#define KT_TILES 8        // 256 / 32

#define GEMM_THREADS 768
#define GEMM_WAVES   12
#define EPB (GEMM_WAVES * 32)   // 384 edges per block-batch

typedef float  f32x4  __attribute__((ext_vector_type(4)));
typedef __bf16 bf16x8 __attribute__((ext_vector_type(8)));

__device__ __forceinline__ unsigned short bf16rne(float f) {
    unsigned int u = __float_as_uint(f);
    u += 0x7FFFu + ((u >> 16) & 1u);
    return (unsigned short)(u >> 16);
}

// ---------------------------------------------------------------------------
// Pack W_e/W_n (256x96 fp32 row-major) into bf16 MFMA B-fragment order.
// ---------------------------------------------------------------------------
__global__ void pack_w_kernel(const float* __restrict__ We,
                              const float* __restrict__ Wn,
                              unsigned short* __restrict__ bpack) {
    int t = blockIdx.x * blockDim.x + threadIdx.x;
    if (t >= KT_TILES * NT_TILES * 64) return;
    int tile = t >> 6, lane = t & 63;
    int kt = tile / NT_TILES, nt = tile % NT_TILES;
    const float* W = (nt < 6) ? We : Wn;
    int n  = (nt % 6) * 16 + (lane & 15);
    int k0 = kt * 32 + (lane >> 4) * 8;
    union { unsigned short u[8]; uint4 v; } tmp;
#pragma unroll
    for (int j = 0; j < 8; ++j) tmp.u[j] = bf16rne(W[(k0 + j) * NODE_DIM + n]);
    *(uint4*)(bpack + (size_t)t * 8) = tmp.v;
}

// ---------------------------------------------------------------------------
// h (N x 96 fp32) -> hb (N x 96 bf16)
// ---------------------------------------------------------------------------
__global__ void cvt_h_kernel(const float* __restrict__ h,
                             unsigned short* __restrict__ hb, int total8) {
    int i = blockIdx.x * 256 + threadIdx.x;
    if (i >= total8) return;
    const float4 v0 = ((const float4*)h)[i * 2];
    const float4 v1 = ((const float4*)h)[i * 2 + 1];
    union { unsigned short u[8]; uint4 v; } p;
    p.u[0] = bf16rne(v0.x); p.u[1] = bf16rne(v0.y);
    p.u[2] = bf16rne(v0.z); p.u[3] = bf16rne(v0.w);
    p.u[4] = bf16rne(v1.x); p.u[5] = bf16rne(v1.y);
    p.u[6] = bf16rne(v1.z); p.u[7] = bf16rne(v1.w);
    ((uint4*)hb)[i] = p.v;
}

// ---------------------------------------------------------------------------
// CSR build: histogram -> exclusive scan -> rank (inverse permutation)
// ---------------------------------------------------------------------------
__global__ void hist_kernel(const int* __restrict__ eidx, unsigned* __restrict__ deg, int E) {
    int e = blockIdx.x * 256 + threadIdx.x;
    if (e < E) atomicAdd(deg + eidx[E + e], 1u);
}

__device__ __forceinline__ unsigned block_excl_scan_256(unsigned v, int tid,
                                                        unsigned* wsum, unsigned* wpre,
                                                        unsigned* total) {
    int lane = tid & 63, w = tid >> 6;
    unsigned inc = v;
#pragma unroll
    for (int o = 1; o < 64; o <<= 1) {
        unsigned t = __shfl_up(inc, o, 64);
        if (lane >= o) inc += t;
    }
    if (lane == 63) wsum[w] = inc;
    __syncthreads();
    if (tid == 0) {
        unsigned s = 0;
#pragma unroll
        for (int k = 0; k < 4; ++k) { wpre[k] = s; s += wsum[k]; }
        *total = s;
    }
    __syncthreads();
    return inc - v + wpre[w];
}

__global__ void scan_block_kernel(const unsigned* __restrict__ deg,
                                  unsigned* __restrict__ scanned,
                                  unsigned* __restrict__ blocksum, int N) {
    __shared__ unsigned wsum[4], wpre[4], total;
    int tid = threadIdx.x;
    int i = blockIdx.x * 256 + tid;
    unsigned v = (i < N) ? deg[i] : 0u;
    unsigned excl = block_excl_scan_256(v, tid, wsum, wpre, &total);
    if (i < N) scanned[i] = excl;
    if (tid == 0) blocksum[blockIdx.x] = total;
}

__global__ void scan_sums_kernel(const unsigned* __restrict__ blocksum,
                                 unsigned* __restrict__ blockpref, int NB) {
    __shared__ unsigned wsum[4], wpre[4], total;
    int tid = threadIdx.x;
    unsigned v = (tid < NB) ? blocksum[tid] : 0u;
    unsigned excl = block_excl_scan_256(v, tid, wsum, wpre, &total);
    if (tid < NB) blockpref[tid] = excl;
}

__global__ void scan_finalize_kernel(const unsigned* __restrict__ scanned,
                                     const unsigned* __restrict__ blockpref,
                                     unsigned* __restrict__ offsets,
                                     unsigned* __restrict__ cursor, int N, int E) {
    int i = blockIdx.x * 256 + threadIdx.x;
    if (i < N) {
        unsigned o = scanned[i] + blockpref[i >> 8];
        offsets[i] = o;
        cursor[i]  = o;
    }
    if (i == 0) offsets[N] = (unsigned)E;
}

__global__ void scatter_kernel(const int* __restrict__ eidx,
                               unsigned* __restrict__ cursor,
                               unsigned* __restrict__ rank, int E) {
    int e = blockIdx.x * 256 + threadIdx.x;
    if (e < E) {
        int d = eidx[E + e];
        rank[e] = atomicAdd(cursor + d, 1u);
    }
}

// ---------------------------------------------------------------------------
// Pass B: per-edge GEMM + activation -> bf16 msg at CSR position rank[e].
// Block = 768 threads = 12 waves; bpack staged once into 96 KB LDS, then each
// wave free-runs (no barriers) over 32-edge tiles (mt=2) in a grid-stride
// batch loop. B-fragment reads are contiguous ds_read_b128 -> 0 conflicts.
// ---------------------------------------------------------------------------
__global__ __launch_bounds__(GEMM_THREADS, 3)
void gemm_msg_kernel(const unsigned short* __restrict__ hb,
                     const int*   __restrict__ eidx,
                     const float* __restrict__ ea,
                     const unsigned short* __restrict__ bpack,
                     const float* __restrict__ be,
                     const float* __restrict__ bn,
                     const unsigned* __restrict__ rank,
                     unsigned short* __restrict__ msg,
                     int E) {
    __shared__ bf16x8 Blds[KT_TILES * NT_TILES * 64];   // 6144 frags = 96 KB

    const int tid = threadIdx.x;

    // ---- stage B: linear 96 KB copy, layout identical to global bpack ----
    {
        const uint4* bsrc = (const uint4*)bpack;
        uint4*       bdst = (uint4*)Blds;
#pragma unroll
        for (int i = 0; i < (KT_TILES * NT_TILES * 64) / GEMM_THREADS; ++i)
            bdst[tid + i * GEMM_THREADS] = bsrc[tid + i * GEMM_THREADS];
    }
    __syncthreads();   // only barrier; B is read-only afterwards

    const int wave = tid >> 6, lane = tid & 63;
    const int m    = lane & 15;
    const int quad = lane >> 4;
    const bf16x8* bl = Blds + lane;

    for (int b0 = blockIdx.x * EPB; b0 < E; b0 += gridDim.x * EPB) {
        const int base = b0 + wave * 32;

        const unsigned short* hsq[2];
        const unsigned short* hdq[2];
        const float*          epq[2];
#pragma unroll
        for (int mt = 0; mt < 2; ++mt) {
            int e  = base + mt * 16 + m;
            int eg = (e < E) ? e : (E - 1);
            int src = eidx[eg];
            int dst = eidx[E + eg];
            hsq[mt] = hb + (size_t)src * NODE_DIM + quad * 8;
            hdq[mt] = hb + (size_t)dst * NODE_DIM + quad * 8;
            epq[mt] = ea + (size_t)eg  * EDGE_DIM + quad * 8;
        }

        f32x4 acc[2][NT_TILES];
#pragma unroll
        for (int mt = 0; mt < 2; ++mt)
#pragma unroll
            for (int nt = 0; nt < NT_TILES; ++nt) acc[mt][nt] = (f32x4){0.f, 0.f, 0.f, 0.f};

#pragma unroll
        for (int kt = 0; kt < KT_TILES; ++kt) {
            bf16x8 A[2];
#pragma unroll
            for (int mt = 0; mt < 2; ++mt) {
                if (kt < 3) {
                    A[mt] = *(const bf16x8*)(hsq[mt] + kt * 32);
                } else if (kt < 6) {
                    A[mt] = *(const bf16x8*)(hdq[mt] + (kt - 3) * 32);
                } else {
                    const float4 v0 = *(const float4*)(epq[mt] + (kt - 6) * 32);
                    const float4 v1 = *(const float4*)(epq[mt] + (kt - 6) * 32 + 4);
                    union { unsigned short u[8]; bf16x8 b; } t;
                    t.u[0] = bf16rne(v0.x); t.u[1] = bf16rne(v0.y);
                    t.u[2] = bf16rne(v0.z); t.u[3] = bf16rne(v0.w);
                    t.u[4] = bf16rne(v1.x); t.u[5] = bf16rne(v1.y);
                    t.u[6] = bf16rne(v1.z); t.u[7] = bf16rne(v1.w);
                    A[mt] = t.b;
                }
            }
#pragma unroll
            for (int nt = 0; nt < NT_TILES; ++nt) {
                bf16x8 bfrag = bl[(kt * NT_TILES + nt) * 64];   // ds_read_b128
                acc[0][nt] = __builtin_amdgcn_mfma_f32_16x16x32_bf16(A[0], bfrag, acc[0][nt], 0, 0, 0);
                acc[1][nt] = __builtin_amdgcn_mfma_f32_16x16x32_bf16(A[1], bfrag, acc[1][nt], 0, 0, 0);
            }
        }

        // epilogue: C layout col = nt*16 + m, row-in-tile = quad*4 + r
#pragma unroll
        for (int mt = 0; mt < 2; ++mt) {
#pragma unroll
            for (int r = 0; r < 4; ++r) {
                const int ee = base + mt * 16 + quad * 4 + r;
                if (ee >= E) continue;
                const size_t prow = (size_t)rank[ee] * NODE_DIM;
#pragma unroll
                for (int nt = 0; nt < 6; ++nt) {
                    const int col = nt * 16 + m;
                    float g  = acc[mt][nt][r]     + be[col];
                    float mm = acc[mt][nt + 6][r] + bn[col];
                    float gate = 1.0f / (1.0f + __expf(-g));
                    float sp   = fmaxf(mm, 0.0f) + __logf(1.0f + __expf(-fabsf(mm)));
                    msg[prow + col] = bf16rne(gate * sp);
                }
            }
        }
    }
}

// ---------------------------------------------------------------------------
// Pass C: streaming CSR reduce. Thread = (node, 8-col group): 12 threads/node,
// 16B loads, rows contiguous at offsets[n]..offsets[n+1].
// ---------------------------------------------------------------------------
__global__ __launch_bounds__(256)
void aggregate_kernel(const float* __restrict__ h,
                      const unsigned* __restrict__ offsets,
                      const unsigned short* __restrict__ msg,
                      float* __restrict__ out, int N) {
    int t = blockIdx.x * 256 + threadIdx.x;
    int n = t / 12, g = t % 12;
    if (n >= N) return;

    const unsigned o0 = offsets[n];
    const unsigned o1 = offsets[n + 1];
    const int deg = (int)(o1 - o0);

    float s0 = 0.f, s1 = 0.f, s2 = 0.f, s3 = 0.f;
    float s4 = 0.f, s5 = 0.f, s6 = 0.f, s7 = 0.f;
    for (unsigned k = o0; k < o1; ++k) {
        const uint4 v = *(const uint4*)(msg + (size_t)k * NODE_DIM + g * 8);
        s0 += __uint_as_float((v.x & 0xFFFFu) << 16);
        s1 += __uint_as_float(v.x & 0xFFFF0000u);
        s2 += __uint_as_float((v.y & 0xFFFFu) << 16);
        s3 += __uint_as_float(v.y & 0xFFFF0000u);
        s4 += __uint_as_float((v.z & 0xFFFFu) << 16);
        s5 += __uint_as_float(v.z & 0xFFFF0000u);
        s6 += __uint_as_float((v.w & 0xFFFFu) << 16);
        s7 += __uint_as_float(v.w & 0xFFFF0000u);
    }
    const float inv = 1.0f / (float)((deg > 0) ? deg : 1);
    const size_t basei = (size_t)n * NODE_DIM + g * 8;
    const float4 h0 = *(const float4*)(h + basei);
    const float4 h1 = *(const float4*)(h + basei + 4);
    float4 o0v = {h0.x + s0 * inv, h0.y + s1 * inv, h0.z + s2 * inv, h0.w + s3 * inv};
    float4 o1v = {h1.x + s4 * inv, h1.y + s5 * inv, h1.z + s6 * inv, h1.w + s7 * inv};
    *(float4*)(out + basei)     = o0v;
    *(float4*)(out + basei + 4) = o1v;
}

// ---------------------------------------------------------------------------
// Fallback (atomic path) if workspace is too small for the CSR pipeline.
// ---------------------------------------------------------------------------
#define TILE_E 64
__global__ __launch_bounds__(256, 4)
void cgconv_atomic_kernel(const float* __restrict__ h,
                          const int*   __restrict__ eidx,
                          const float* __restrict__ ea,
                          const unsigned short* __restrict__ bpack,
                          const float* __restrict__ be,
                          const float* __restrict__ bn,
                          float* __restrict__ hnew,
                          float* __restrict__ cnt,
                          int E) {
    const int tid  = threadIdx.x;
    const int wave = tid >> 6, lane = tid & 63;
    const int m    = lane & 15;
    const int quad = lane >> 4;

    const int e  = blockIdx.x * TILE_E + wave * 16 + m;
    const int eg = (e < E) ? e : (E - 1);
    const int src = eidx[eg];
    const int dst = eidx[E + eg];
    if (quad == 0 && e < E) unsafeAtomicAdd(cnt + dst, 1.0f);

    f32x4 acc[NT_TILES];
#pragma unroll
    for (int nt = 0; nt < NT_TILES; ++nt) acc[nt] = (f32x4){0.f, 0.f, 0.f, 0.f};

    const float* hsrc = h + (size_t)src * NODE_DIM;
    const float* hdst = h + (size_t)dst * NODE_DIM;
    const float* earo = ea + (size_t)eg * EDGE_DIM;

#pragma unroll
    for (int kt = 0; kt < KT_TILES; ++kt) {
        const int ko = kt * 32 + quad * 8;
        const float* p;
        if (kt < 3)      p = hsrc + ko;
        else if (kt < 6) p = hdst + (ko - NODE_DIM);
        else             p = earo + (ko - 2 * NODE_DIM);
        const float4 v0 = *(const float4*)p;
        const float4 v1 = *(const float4*)(p + 4);
        union { unsigned short u[8]; bf16x8 b; } A;
        A.u[0] = bf16rne(v0.x); A.u[1] = bf16rne(v0.y);
        A.u[2] = bf16rne(v0.z); A.u[3] = bf16rne(v0.w);
        A.u[4] = bf16rne(v1.x); A.u[5] = bf16rne(v1.y);
        A.u[6] = bf16rne(v1.z); A.u[7] = bf16rne(v1.w);
#pragma unroll
        for (int nt = 0; nt < NT_TILES; ++nt) {
            bf16x8 bfrag = *(const bf16x8*)(bpack +
                             (size_t)((kt * NT_TILES + nt) * 64 + lane) * 8);
            acc[nt] = __builtin_amdgcn_mfma_f32_16x16x32_bf16(A.b, bfrag, acc[nt], 0, 0, 0);
        }
    }

    int drow[4], erow[4];
#pragma unroll
    for (int r = 0; r < 4; ++r) {
        drow[r] = __shfl(dst, quad * 4 + r, 64);
        erow[r] = blockIdx.x * TILE_E + wave * 16 + quad * 4 + r;
    }
#pragma unroll
    for (int nt = 0; nt < 6; ++nt) {
        const int col = nt * 16 + m;
        const float bev = be[col];
        const float bnv = bn[col];
#pragma unroll
        for (int r = 0; r < 4; ++r) {
            if (erow[r] >= E) continue;
            float g  = acc[nt][r] + bev;
            float mm = acc[nt + 6][r] + bnv;
            float gate = 1.0f / (1.0f + __expf(-g));
            float sp   = fmaxf(mm, 0.0f) + __logf(1.0f + __expf(-fabsf(mm)));
            unsafeAtomicAdd(hnew + (size_t)drow[r] * NODE_DIM + col, gate * sp);
        }
    }
}

__global__ void finalize_kernel(const float* __restrict__ h,
                                const float* __restrict__ hnew,
                                const float* __restrict__ cnt,
                                float* __restrict__ out,
                                int total4) {
    int i = blockIdx.x * blockDim.x + threadIdx.x;
    if (i >= total4) return;
    int n = i / 24;
    float inv = 1.0f / fmaxf(cnt[n], 1.0f);
    float4 hv = ((const float4*)h)[i];
    float4 av = ((const float4*)hnew)[i];
    float4 o = {hv.x + av.x * inv, hv.y + av.y * inv, hv.z + av.z * inv, hv.w + av.w * inv};
    ((float4*)out)[i] = o;
}

// ---------------------------------------------------------------------------
extern "C" void kernel_launch(void* const* d_in, const int* in_sizes, int n_in,
                              void* d_out, int out_size, void* d_ws, size_t ws_size,
                              hipStream_t stream) {
    const float* h   = (const float*)d_in[0];
    const int*   ei  = (const int*)  d_in[1];
    const float* ea  = (const float*)d_in[2];
    const float* We  = (const float*)d_in[3];
    const float* be  = (const float*)d_in[4];
    const float* Wn  = (const float*)d_in[5];
    const float* bn  = (const float*)d_in[6];

    const int N = in_sizes[0] / NODE_DIM;     // 50000
    const int E = in_sizes[2] / EDGE_DIM;     // 800000
    char* ws = (char*)d_ws;

    size_t off = 0;
    auto take = [&](size_t bytes) { size_t o = off; off = (off + bytes + 511) & ~(size_t)511; return o; };
    const size_t O_BPACK  = take((size_t)KT_TILES * NT_TILES * 64 * 16);   // 96 KB
    const size_t O_DEG    = take((size_t)N * 4);
    const size_t O_SCAN   = take((size_t)N * 4);
    const size_t O_BSUM   = take(1024);
    const size_t O_BPREF  = take(1024);
    const size_t O_OFFS   = take((size_t)(N + 1) * 4);
    const size_t O_CURS   = take((size_t)N * 4);
    const size_t O_RANK   = take((size_t)E * 4);
    const size_t O_HB     = take((size_t)N * NODE_DIM * 2);               // 9.6 MB
    const size_t O_MSG    = take((size_t)E * NODE_DIM * 2);               // 153.6 MB
    const size_t NEED = off;

    unsigned short* bpack = (unsigned short*)(ws + O_BPACK);
    pack_w_kernel<<<(KT_TILES * NT_TILES * 64 + 255) / 256, 256, 0, stream>>>(We, Wn, bpack);

    if (ws_size >= NEED) {
        unsigned* deg    = (unsigned*)(ws + O_DEG);
        unsigned* scn    = (unsigned*)(ws + O_SCAN);
        unsigned* bsum   = (unsigned*)(ws + O_BSUM);
        unsigned* bpref  = (unsigned*)(ws + O_BPREF);
        unsigned* offs   = (unsigned*)(ws + O_OFFS);
        unsigned* curs   = (unsigned*)(ws + O_CURS);
        unsigned* rank   = (unsigned*)(ws + O_RANK);
        unsigned short* hb  = (unsigned short*)(ws + O_HB);
        unsigned short* msg = (unsigned short*)(ws + O_MSG);

        hipMemsetAsync(deg, 0, (size_t)N * 4, stream);

        const int total8 = N * NODE_DIM / 8;   // 600000
        cvt_h_kernel<<<(total8 + 255) / 256, 256, 0, stream>>>(h, hb, total8);

        const int NB = (N + 255) / 256;
        hist_kernel<<<(E + 255) / 256, 256, 0, stream>>>(ei, deg, E);
        scan_block_kernel<<<NB, 256, 0, stream>>>(deg, scn, bsum, N);
        scan_sums_kernel<<<1, 256, 0, stream>>>(bsum, bpref, NB);
        scan_finalize_kernel<<<NB, 256, 0, stream>>>(scn, bpref, offs, curs, N, E);
        scatter_kernel<<<(E + 255) / 256, 256, 0, stream>>>(ei, curs, rank, E);

        // persistent-ish: 256 blocks (1/CU, LDS-capped), grid-stride over batches
        gemm_msg_kernel<<<256, GEMM_THREADS, 0, stream>>>(hb, ei, ea, bpack, be, bn, rank, msg, E);

        const int aggthreads = N * 12;
        aggregate_kernel<<<(aggthreads + 255) / 256, 256, 0, stream>>>(h, offs, msg, (float*)d_out, N);
    } else {
        size_t cnt_off  = O_DEG;
        size_t hnew_off = (cnt_off + (size_t)N * 4 + 511) & ~(size_t)511;
        float* cnt  = (float*)(ws + cnt_off);
        float* hnew = (float*)(ws + hnew_off);
        hipMemsetAsync(ws + cnt_off, 0, hnew_off - cnt_off + (size_t)N * NODE_DIM * 4, stream);
        cgconv_atomic_kernel<<<(E + TILE_E - 1) / TILE_E, 256, 0, stream>>>(
            h, ei, ea, bpack, be, bn, hnew, cnt, E);
        const int total4 = N * (NODE_DIM / 4);
        finalize_kernel<<<(total4 + 255) / 256, 256, 0, stream>>>(h, hnew, cnt, (float*)d_out, total4);
    }
}

// Round 2
// 707.054 us; speedup vs baseline: 1.9848x; 1.9848x over previous
//
#include <hip/hip_runtime.h>
#include <hip/hip_bf16.h>

// CGConv fused for MI355X (gfx950) — round 7.
//   gemm: whole packed B (96 KB = 384 VGPR/lane) preloaded into the unified
//         VGPR/AGPR file of persistent 1-wave blocks (launch_bounds(64,1),
//         grid=1024 => 1 wave/SIMD, 4 blocks/CU). Inner loop has ZERO B
//         loads: 16 edges/iter, 96 MFMAs fed from registers. Round 6's LDS
//         experiment showed geometry changes wreck L2 behavior (FETCH 261MB
//         -> 1.7GB), so the memory streams (hb gather, ea stream, msg
//         scatter) keep round 5's per-wave shape and a contiguous 16K-edge
//         instantaneous window.
//   CSR:  scatter produces inverse-perm rank[e]; gemm writes msg rows directly
//         at CSR position -> aggregate is a contiguous vectorized stream.
//         (identical to round 5)

#define NODE_DIM 96
#define EDGE_DIM 64
#define IN_DIM   256
#define NT_TILES 12       // 192 output cols = 96 gates + 96 msgs
#define KT_TILES 8        // 256 / 32

#define GEMM_GRID 1024    // persistent 1-wave blocks: 256 CU * 4 SIMD

typedef float  f32x4  __attribute__((ext_vector_type(4)));
typedef __bf16 bf16x8 __attribute__((ext_vector_type(8)));

__device__ __forceinline__ unsigned short bf16rne(float f) {
    unsigned int u = __float_as_uint(f);
    u += 0x7FFFu + ((u >> 16) & 1u);
    return (unsigned short)(u >> 16);
}

// ---------------------------------------------------------------------------
// Pack W_e/W_n (256x96 fp32 row-major) into bf16 MFMA B-fragment order.
// ---------------------------------------------------------------------------
__global__ void pack_w_kernel(const float* __restrict__ We,
                              const float* __restrict__ Wn,
                              unsigned short* __restrict__ bpack) {
    int t = blockIdx.x * blockDim.x + threadIdx.x;
    if (t >= KT_TILES * NT_TILES * 64) return;
    int tile = t >> 6, lane = t & 63;
    int kt = tile / NT_TILES, nt = tile % NT_TILES;
    const float* W = (nt < 6) ? We : Wn;
    int n  = (nt % 6) * 16 + (lane & 15);
    int k0 = kt * 32 + (lane >> 4) * 8;
    union { unsigned short u[8]; uint4 v; } tmp;
#pragma unroll
    for (int j = 0; j < 8; ++j) tmp.u[j] = bf16rne(W[(k0 + j) * NODE_DIM + n]);
    *(uint4*)(bpack + (size_t)t * 8) = tmp.v;
}

// ---------------------------------------------------------------------------
// h (N x 96 fp32) -> hb (N x 96 bf16)
// ---------------------------------------------------------------------------
__global__ void cvt_h_kernel(const float* __restrict__ h,
                             unsigned short* __restrict__ hb, int total8) {
    int i = blockIdx.x * 256 + threadIdx.x;
    if (i >= total8) return;
    const float4 v0 = ((const float4*)h)[i * 2];
    const float4 v1 = ((const float4*)h)[i * 2 + 1];
    union { unsigned short u[8]; uint4 v; } p;
    p.u[0] = bf16rne(v0.x); p.u[1] = bf16rne(v0.y);
    p.u[2] = bf16rne(v0.z); p.u[3] = bf16rne(v0.w);
    p.u[4] = bf16rne(v1.x); p.u[5] = bf16rne(v1.y);
    p.u[6] = bf16rne(v1.z); p.u[7] = bf16rne(v1.w);
    ((uint4*)hb)[i] = p.v;
}

// ---------------------------------------------------------------------------
// CSR build: histogram -> exclusive scan -> rank (inverse permutation)
// ---------------------------------------------------------------------------
__global__ void hist_kernel(const int* __restrict__ eidx, unsigned* __restrict__ deg, int E) {
    int e = blockIdx.x * 256 + threadIdx.x;
    if (e < E) atomicAdd(deg + eidx[E + e], 1u);
}

__device__ __forceinline__ unsigned block_excl_scan_256(unsigned v, int tid,
                                                        unsigned* wsum, unsigned* wpre,
                                                        unsigned* total) {
    int lane = tid & 63, w = tid >> 6;
    unsigned inc = v;
#pragma unroll
    for (int o = 1; o < 64; o <<= 1) {
        unsigned t = __shfl_up(inc, o, 64);
        if (lane >= o) inc += t;
    }
    if (lane == 63) wsum[w] = inc;
    __syncthreads();
    if (tid == 0) {
        unsigned s = 0;
#pragma unroll
        for (int k = 0; k < 4; ++k) { wpre[k] = s; s += wsum[k]; }
        *total = s;
    }
    __syncthreads();
    return inc - v + wpre[w];
}

__global__ void scan_block_kernel(const unsigned* __restrict__ deg,
                                  unsigned* __restrict__ scanned,
                                  unsigned* __restrict__ blocksum, int N) {
    __shared__ unsigned wsum[4], wpre[4], total;
    int tid = threadIdx.x;
    int i = blockIdx.x * 256 + tid;
    unsigned v = (i < N) ? deg[i] : 0u;
    unsigned excl = block_excl_scan_256(v, tid, wsum, wpre, &total);
    if (i < N) scanned[i] = excl;
    if (tid == 0) blocksum[blockIdx.x] = total;
}

__global__ void scan_sums_kernel(const unsigned* __restrict__ blocksum,
                                 unsigned* __restrict__ blockpref, int NB) {
    __shared__ unsigned wsum[4], wpre[4], total;
    int tid = threadIdx.x;
    unsigned v = (tid < NB) ? blocksum[tid] : 0u;
    unsigned excl = block_excl_scan_256(v, tid, wsum, wpre, &total);
    if (tid < NB) blockpref[tid] = excl;
}

__global__ void scan_finalize_kernel(const unsigned* __restrict__ scanned,
                                     const unsigned* __restrict__ blockpref,
                                     unsigned* __restrict__ offsets,
                                     unsigned* __restrict__ cursor, int N, int E) {
    int i = blockIdx.x * 256 + threadIdx.x;
    if (i < N) {
        unsigned o = scanned[i] + blockpref[i >> 8];
        offsets[i] = o;
        cursor[i]  = o;
    }
    if (i == 0) offsets[N] = (unsigned)E;
}

__global__ void scatter_kernel(const int* __restrict__ eidx,
                               unsigned* __restrict__ cursor,
                               unsigned* __restrict__ rank, int E) {
    int e = blockIdx.x * 256 + threadIdx.x;
    if (e < E) {
        int d = eidx[E + e];
        rank[e] = atomicAdd(cursor + d, 1u);
    }
}

// ---------------------------------------------------------------------------
// Pass B: per-edge GEMM + activation -> bf16 msg at CSR position rank[e].
// Persistent 1-wave blocks; entire packed B lives in registers (96 frags =
// 384 VGPR/lane). launch_bounds(64,1) -> 512-reg budget, 1 wave/SIMD.
// Inner loop: 16 edges, A-gather + 96 reg-fed MFMAs + activation epilogue.
// ---------------------------------------------------------------------------
__global__ __launch_bounds__(64, 1)
void gemm_msg_kernel(const unsigned short* __restrict__ hb,
                     const int*   __restrict__ eidx,
                     const float* __restrict__ ea,
                     const unsigned short* __restrict__ bpack,
                     const float* __restrict__ be,
                     const float* __restrict__ bn,
                     const unsigned* __restrict__ rank,
                     unsigned short* __restrict__ msg,
                     int E) {
    const int lane = threadIdx.x;       // 0..63, block = 1 wave
    const int m    = lane & 15;
    const int quad = lane >> 4;

    // ---- preload ALL of packed B into registers: 96 x bf16x8 = 384 regs ----
    bf16x8 B[KT_TILES][NT_TILES];
    {
        const bf16x8* bp = (const bf16x8*)bpack + lane;
#pragma unroll
        for (int kt = 0; kt < KT_TILES; ++kt)
#pragma unroll
            for (int nt = 0; nt < NT_TILES; ++nt)
                B[kt][nt] = bp[(kt * NT_TILES + nt) * 64];
    }

    // bias slices for this lane's output columns (static, 12 regs)
    float bev[6], bnv[6];
#pragma unroll
    for (int nt = 0; nt < 6; ++nt) {
        bev[nt] = be[nt * 16 + m];
        bnv[nt] = bn[nt * 16 + m];
    }

    const int STRIDE = GEMM_GRID * 16;
    for (int base = blockIdx.x * 16; base < E; base += STRIDE) {
        const int e  = base + m;
        const int eg = (e < E) ? e : (E - 1);
        const int src = eidx[eg];
        const int dst = eidx[E + eg];
        const unsigned short* hs = hb + (size_t)src * NODE_DIM + quad * 8;
        const unsigned short* hd = hb + (size_t)dst * NODE_DIM + quad * 8;
        const float*          ep = ea + (size_t)eg  * EDGE_DIM + quad * 8;

        f32x4 acc[NT_TILES];
#pragma unroll
        for (int nt = 0; nt < NT_TILES; ++nt) acc[nt] = (f32x4){0.f, 0.f, 0.f, 0.f};

#pragma unroll
        for (int kt = 0; kt < KT_TILES; ++kt) {
            bf16x8 A;
            if (kt < 3) {
                A = *(const bf16x8*)(hs + kt * 32);
            } else if (kt < 6) {
                A = *(const bf16x8*)(hd + (kt - 3) * 32);
            } else {
                const float4 v0 = *(const float4*)(ep + (kt - 6) * 32);
                const float4 v1 = *(const float4*)(ep + (kt - 6) * 32 + 4);
                union { unsigned short u[8]; bf16x8 b; } t;
                t.u[0] = bf16rne(v0.x); t.u[1] = bf16rne(v0.y);
                t.u[2] = bf16rne(v0.z); t.u[3] = bf16rne(v0.w);
                t.u[4] = bf16rne(v1.x); t.u[5] = bf16rne(v1.y);
                t.u[6] = bf16rne(v1.z); t.u[7] = bf16rne(v1.w);
                A = t.b;
            }
#pragma unroll
            for (int nt = 0; nt < NT_TILES; ++nt)
                acc[nt] = __builtin_amdgcn_mfma_f32_16x16x32_bf16(A, B[kt][nt], acc[nt], 0, 0, 0);
        }

        // epilogue: C layout col = nt*16 + m, row-in-tile = quad*4 + r
#pragma unroll
        for (int r = 0; r < 4; ++r) {
            const int ee = base + quad * 4 + r;
            if (ee >= E) continue;
            const size_t prow = (size_t)rank[ee] * NODE_DIM;
#pragma unroll
            for (int nt = 0; nt < 6; ++nt) {
                const int col = nt * 16 + m;
                float g  = acc[nt][r]     + bev[nt];
                float mm = acc[nt + 6][r] + bnv[nt];
                float gate = 1.0f / (1.0f + __expf(-g));
                float sp   = fmaxf(mm, 0.0f) + __logf(1.0f + __expf(-fabsf(mm)));
                msg[prow + col] = bf16rne(gate * sp);
            }
        }
    }
}

// ---------------------------------------------------------------------------
// Pass C: streaming CSR reduce. Thread = (node, 8-col group): 12 threads/node,
// 16B loads, rows contiguous at offsets[n]..offsets[n+1].
// ---------------------------------------------------------------------------
__global__ __launch_bounds__(256)
void aggregate_kernel(const float* __restrict__ h,
                      const unsigned* __restrict__ offsets,
                      const unsigned short* __restrict__ msg,
                      float* __restrict__ out, int N) {
    int t = blockIdx.x * 256 + threadIdx.x;
    int n = t / 12, g = t % 12;
    if (n >= N) return;

    const unsigned o0 = offsets[n];
    const unsigned o1 = offsets[n + 1];
    const int deg = (int)(o1 - o0);

    float s0 = 0.f, s1 = 0.f, s2 = 0.f, s3 = 0.f;
    float s4 = 0.f, s5 = 0.f, s6 = 0.f, s7 = 0.f;
    for (unsigned k = o0; k < o1; ++k) {
        const uint4 v = *(const uint4*)(msg + (size_t)k * NODE_DIM + g * 8);
        s0 += __uint_as_float((v.x & 0xFFFFu) << 16);
        s1 += __uint_as_float(v.x & 0xFFFF0000u);
        s2 += __uint_as_float((v.y & 0xFFFFu) << 16);
        s3 += __uint_as_float(v.y & 0xFFFF0000u);
        s4 += __uint_as_float((v.z & 0xFFFFu) << 16);
        s5 += __uint_as_float(v.z & 0xFFFF0000u);
        s6 += __uint_as_float((v.w & 0xFFFFu) << 16);
        s7 += __uint_as_float(v.w & 0xFFFF0000u);
    }
    const float inv = 1.0f / (float)((deg > 0) ? deg : 1);
    const size_t basei = (size_t)n * NODE_DIM + g * 8;
    const float4 h0 = *(const float4*)(h + basei);
    const float4 h1 = *(const float4*)(h + basei + 4);
    float4 o0v = {h0.x + s0 * inv, h0.y + s1 * inv, h0.z + s2 * inv, h0.w + s3 * inv};
    float4 o1v = {h1.x + s4 * inv, h1.y + s5 * inv, h1.z + s6 * inv, h1.w + s7 * inv};
    *(float4*)(out + basei)     = o0v;
    *(float4*)(out + basei + 4) = o1v;
}

// ---------------------------------------------------------------------------
// Fallback (atomic path) if workspace is too small for the CSR pipeline.
// ---------------------------------------------------------------------------
#define TILE_E 64
__global__ __launch_bounds__(256, 4)
void cgconv_atomic_kernel(const float* __restrict__ h,
                          const int*   __restrict__ eidx,
                          const float* __restrict__ ea,
                          const unsigned short* __restrict__ bpack,
                          const float* __restrict__ be,
                          const float* __restrict__ bn,
                          float* __restrict__ hnew,
                          float* __restrict__ cnt,
                          int E) {
    const int tid  = threadIdx.x;
    const int wave = tid >> 6, lane = tid & 63;
    const int m    = lane & 15;
    const int quad = lane >> 4;

    const int e  = blockIdx.x * TILE_E + wave * 16 + m;
    const int eg = (e < E) ? e : (E - 1);
    const int src = eidx[eg];
    const int dst = eidx[E + eg];
    if (quad == 0 && e < E) unsafeAtomicAdd(cnt + dst, 1.0f);

    f32x4 acc[NT_TILES];
#pragma unroll
    for (int nt = 0; nt < NT_TILES; ++nt) acc[nt] = (f32x4){0.f, 0.f, 0.f, 0.f};

    const float* hsrc = h + (size_t)src * NODE_DIM;
    const float* hdst = h + (size_t)dst * NODE_DIM;
    const float* earo = ea + (size_t)eg * EDGE_DIM;

#pragma unroll
    for (int kt = 0; kt < KT_TILES; ++kt) {
        const int ko = kt * 32 + quad * 8;
        const float* p;
        if (kt < 3)      p = hsrc + ko;
        else if (kt < 6) p = hdst + (ko - NODE_DIM);
        else             p = earo + (ko - 2 * NODE_DIM);
        const float4 v0 = *(const float4*)p;
        const float4 v1 = *(const float4*)(p + 4);
        union { unsigned short u[8]; bf16x8 b; } A;
        A.u[0] = bf16rne(v0.x); A.u[1] = bf16rne(v0.y);
        A.u[2] = bf16rne(v0.z); A.u[3] = bf16rne(v0.w);
        A.u[4] = bf16rne(v1.x); A.u[5] = bf16rne(v1.y);
        A.u[6] = bf16rne(v1.z); A.u[7] = bf16rne(v1.w);
#pragma unroll
        for (int nt = 0; nt < NT_TILES; ++nt) {
            bf16x8 bfrag = *(const bf16x8*)(bpack +
                             (size_t)((kt * NT_TILES + nt) * 64 + lane) * 8);
            acc[nt] = __builtin_amdgcn_mfma_f32_16x16x32_bf16(A.b, bfrag, acc[nt], 0, 0, 0);
        }
    }

    int drow[4], erow[4];
#pragma unroll
    for (int r = 0; r < 4; ++r) {
        drow[r] = __shfl(dst, quad * 4 + r, 64);
        erow[r] = blockIdx.x * TILE_E + wave * 16 + quad * 4 + r;
    }
#pragma unroll
    for (int nt = 0; nt < 6; ++nt) {
        const int col = nt * 16 + m;
        const float bev = be[col];
        const float bnv = bn[col];
#pragma unroll
        for (int r = 0; r < 4; ++r) {
            if (erow[r] >= E) continue;
            float g  = acc[nt][r] + bev;
            float mm = acc[nt + 6][r] + bnv;
            float gate = 1.0f / (1.0f + __expf(-g));
            float sp   = fmaxf(mm, 0.0f) + __logf(1.0f + __expf(-fabsf(mm)));
            unsafeAtomicAdd(hnew + (size_t)drow[r] * NODE_DIM + col, gate * sp);
        }
    }
}

__global__ void finalize_kernel(const float* __restrict__ h,
                                const float* __restrict__ hnew,
                                const float* __restrict__ cnt,
                                float* __restrict__ out,
                                int total4) {
    int i = blockIdx.x * blockDim.x + threadIdx.x;
    if (i >= total4) return;
    int n = i / 24;
    float inv = 1.0f / fmaxf(cnt[n], 1.0f);
    float4 hv = ((const float4*)h)[i];
    float4 av = ((const float4*)hnew)[i];
    float4 o = {hv.x + av.x * inv, hv.y + av.y * inv, hv.z + av.z * inv, hv.w + av.w * inv};
    ((float4*)out)[i] = o;
}

// ---------------------------------------------------------------------------
extern "C" void kernel_launch(void* const* d_in, const int* in_sizes, int n_in,
                              void* d_out, int out_size, void* d_ws, size_t ws_size,
                              hipStream_t stream) {
    const float* h   = (const float*)d_in[0];
    const int*   ei  = (const int*)  d_in[1];
    const float* ea  = (const float*)d_in[2];
    const float* We  = (const float*)d_in[3];
    const float* be  = (const float*)d_in[4];
    const float* Wn  = (const float*)d_in[5];
    const float* bn  = (const float*)d_in[6];

    const int N = in_sizes[0] / NODE_DIM;     // 50000
    const int E = in_sizes[2] / EDGE_DIM;     // 800000
    char* ws = (char*)d_ws;

    size_t off = 0;
    auto take = [&](size_t bytes) { size_t o = off; off = (off + bytes + 511) & ~(size_t)511; return o; };
    const size_t O_BPACK  = take((size_t)KT_TILES * NT_TILES * 64 * 16);   // 96 KB
    const size_t O_DEG    = take((size_t)N * 4);
    const size_t O_SCAN   = take((size_t)N * 4);
    const size_t O_BSUM   = take(1024);
    const size_t O_BPREF  = take(1024);
    const size_t O_OFFS   = take((size_t)(N + 1) * 4);
    const size_t O_CURS   = take((size_t)N * 4);
    const size_t O_RANK   = take((size_t)E * 4);
    const size_t O_HB     = take((size_t)N * NODE_DIM * 2);               // 9.6 MB
    const size_t O_MSG    = take((size_t)E * NODE_DIM * 2);               // 153.6 MB
    const size_t NEED = off;

    unsigned short* bpack = (unsigned short*)(ws + O_BPACK);
    pack_w_kernel<<<(KT_TILES * NT_TILES * 64 + 255) / 256, 256, 0, stream>>>(We, Wn, bpack);

    if (ws_size >= NEED) {
        unsigned* deg    = (unsigned*)(ws + O_DEG);
        unsigned* scn    = (unsigned*)(ws + O_SCAN);
        unsigned* bsum   = (unsigned*)(ws + O_BSUM);
        unsigned* bpref  = (unsigned*)(ws + O_BPREF);
        unsigned* offs   = (unsigned*)(ws + O_OFFS);
        unsigned* curs   = (unsigned*)(ws + O_CURS);
        unsigned* rank   = (unsigned*)(ws + O_RANK);
        unsigned short* hb  = (unsigned short*)(ws + O_HB);
        unsigned short* msg = (unsigned short*)(ws + O_MSG);

        hipMemsetAsync(deg, 0, (size_t)N * 4, stream);

        const int total8 = N * NODE_DIM / 8;   // 600000
        cvt_h_kernel<<<(total8 + 255) / 256, 256, 0, stream>>>(h, hb, total8);

        const int NB = (N + 255) / 256;
        hist_kernel<<<(E + 255) / 256, 256, 0, stream>>>(ei, deg, E);
        scan_block_kernel<<<NB, 256, 0, stream>>>(deg, scn, bsum, N);
        scan_sums_kernel<<<1, 256, 0, stream>>>(bsum, bpref, NB);
        scan_finalize_kernel<<<NB, 256, 0, stream>>>(scn, bpref, offs, curs, N, E);
        scatter_kernel<<<(E + 255) / 256, 256, 0, stream>>>(ei, curs, rank, E);

        // persistent 1-wave blocks, whole B in registers
        gemm_msg_kernel<<<GEMM_GRID, 64, 0, stream>>>(hb, ei, ea, bpack, be, bn, rank, msg, E);

        const int aggthreads = N * 12;
        aggregate_kernel<<<(aggthreads + 255) / 256, 256, 0, stream>>>(h, offs, msg, (float*)d_out, N);
    } else {
        size_t cnt_off  = O_DEG;
        size_t hnew_off = (cnt_off + (size_t)N * 4 + 511) & ~(size_t)511;
        float* cnt  = (float*)(ws + cnt_off);
        float* hnew = (float*)(ws + hnew_off);
        hipMemsetAsync(ws + cnt_off, 0, hnew_off - cnt_off + (size_t)N * NODE_DIM * 4, stream);
        cgconv_atomic_kernel<<<(E + TILE_E - 1) / TILE_E, 256, 0, stream>>>(
            h, ei, ea, bpack, be, bn, hnew, cnt, E);
        const int total4 = N * (NODE_DIM / 4);
        finalize_kernel<<<(total4 + 255) / 256, 256, 0, stream>>>(h, hnew, cnt, (float*)d_out, total4);
    }
}